// Round 5
// baseline (1155.199 us; speedup 1.0000x reference)
//
#include <hip/hip_runtime.h>
#include <math.h>

// Shapes: B=32, S=512, I=64, H=512, E=8, P=96, O=64, EM=512; D = S*I = 32768.
#define DIMK 32768
#define NB 512  // persistent grid: 2 blocks/CU x 256 CUs (LDS 70KB -> 2/CU)

__device__ __forceinline__ void fma4(float4& a, float s, const float4 w) {
  a.x += s * w.x; a.y += s * w.y; a.z += s * w.z; a.w += s * w.w;
}

// device-scope grid barrier (monotone counter, generation = phase*NB).
__device__ __forceinline__ void gsync(unsigned* bar, unsigned target) {
  __syncthreads();
  if (threadIdx.x == 0) {
    __threadfence();  // release: make our writes device-visible
    __hip_atomic_fetch_add(bar, 1u, __ATOMIC_RELEASE, __HIP_MEMORY_SCOPE_AGENT);
    int guard = 0;
    while (__hip_atomic_load(bar, __ATOMIC_ACQUIRE, __HIP_MEMORY_SCOPE_AGENT) < target) {
      __builtin_amdgcn_s_sleep(2);
      if (++guard > 4000000) break;  // degrade to wrong-answer instead of hang
    }
    __threadfence();  // acquire: invalidate stale lines
  }
  __syncthreads();
}

// block sum over 256 threads (wave shuffle + 4-slot LDS combine)
__device__ __forceinline__ float bsum(float v, volatile float* r4) {
  for (int o = 1; o < 64; o <<= 1) v += __shfl_xor(v, o);
  const int w = threadIdx.x >> 6;
  __syncthreads();
  if ((threadIdx.x & 63) == 0) r4[w] = v;
  __syncthreads();
  return r4[0] + r4[1] + r4[2] + r4[3];
}

// LN over 512 cols (2 per thread) of sum_{kq<nq} zp[(kq*32+b)*512+m] + bias
__device__ void redln512(const float* zp, const float* bias, const float* g,
                         const float* bt, float* outp, int b, int nq, int relu,
                         volatile float* r4) {
  const int t = threadIdx.x;
  float a0 = bias[t], a1 = bias[t + 256];
  const float* p = zp + (size_t)b * 512;
#pragma unroll 8
  for (int kq = 0; kq < nq; ++kq) {
    a0 += p[t]; a1 += p[t + 256];
    p += 512 * 32;
  }
  float mean = bsum(a0 + a1, r4) * (1.f / 512.f);
  float d0 = a0 - mean, d1 = a1 - mean;
  float var = bsum(d0 * d0 + d1 * d1, r4) * (1.f / 512.f);
  float rr = rsqrtf(var + 1e-5f);
  float v0 = d0 * rr * g[t] + bt[t];
  float v1 = d1 * rr * g[t + 256] + bt[t + 256];
  outp[b * 512 + t] = relu ? fmaxf(v0, 0.f) : v0;
  outp[b * 512 + t + 256] = relu ? fmaxf(v1, 0.f) : v1;
}

// LN over 256 cols (1 per thread)
__device__ void redln256(const float* zp, const float* bias, const float* g,
                         const float* bt, float* outp, int b, int nq, int relu,
                         volatile float* r4) {
  const int t = threadIdx.x;
  float a = bias[t];
  const float* p = zp + (size_t)b * 256 + t;
#pragma unroll 8
  for (int kq = 0; kq < nq; ++kq) { a += *p; p += 256 * 32; }
  float mean = bsum(a, r4) * (1.f / 256.f);
  float d = a - mean;
  float var = bsum(d * d, r4) * (1.f / 256.f);
  float v = d * rsqrtf(var + 1e-5f) * g[t] + bt[t];
  outp[b * 256 + t] = relu ? fmaxf(v, 0.f) : v;
}

// small GEMM tile: 32 b x 32 m x 32 k, LDS-staged. outp[(kq*32+b)*M + m]
__device__ void sgemm32(const float* A, int aRow, const float* W, int M,
                        float* outp, int mt, int kq, float* S) {
  const int t = threadIdx.x;
  const int m0 = mt * 32, k0 = kq * 32;
  float* Ws = S;           // 32k x 32m = 1024
  float* As = S + 1024;    // 32b x 36  = 1152
  {
    int r = t >> 3, q = t & 7;
    *(float4*)&Ws[r * 32 + q * 4] = *(const float4*)(W + (size_t)(k0 + r) * M + m0 + q * 4);
    *(float4*)&As[r * 36 + q * 4] = *(const float4*)(A + (size_t)r * aRow + k0 + q * 4);
  }
  __syncthreads();
  const int b = t >> 3, mf = t & 7;
  float4 acc = make_float4(0.f, 0.f, 0.f, 0.f);
#pragma unroll
  for (int k = 0; k < 32; ++k)
    fma4(acc, As[b * 36 + k], *(const float4*)&Ws[k * 32 + mf * 4]);
  *(float4*)(outp + ((size_t)kq * 32 + b) * M + m0 + mf * 4) = acc;
  __syncthreads();
}

// expert GEMM tile: 32 b x 64 m x 128 k. outp[b*512 + m] (base pre-offset)
__device__ void egemm(const float* A, const float* W, float* outp,
                      int mt, int kq, float* S) {
  const int t = threadIdx.x;
  const int m0 = mt * 64, k0 = kq * 128;
  float* Ws = S;           // 128k x 64m = 8192
  float* As = S + 8192;    // 32b x 132  = 4224
  for (int i = t; i < 2048; i += 256) {
    int r = i >> 4, q = i & 15;
    *(float4*)&Ws[r * 64 + q * 4] = *(const float4*)(W + (size_t)(k0 + r) * 512 + m0 + q * 4);
  }
  for (int i = t; i < 1024; i += 256) {
    int b = i >> 5, q = i & 31;
    *(float4*)&As[b * 132 + q * 4] = *(const float4*)(A + (size_t)b * 512 + k0 + q * 4);
  }
  __syncthreads();
  const int mf = t & 15, b0 = (t >> 4) * 2;
  float4 a0 = make_float4(0.f, 0.f, 0.f, 0.f), a1 = a0;
  const float* ar0 = As + b0 * 132;
  const float* ar1 = ar0 + 132;
#pragma unroll 4
  for (int k = 0; k < 128; ++k) {
    float4 wv = *(const float4*)&Ws[k * 64 + mf * 4];
    fma4(a0, ar0[k], wv);
    fma4(a1, ar1[k], wv);
  }
  float* op = outp + (size_t)b0 * 512 + m0 + mf * 4;
  *(float4*)op = a0;
  *(float4*)(op + 512) = a1;
  __syncthreads();
}

// pW2 GEMM tile: 32 b x 64 m x 64 k, M=6144. outp[(kq*32+b)*6144 + m]
__device__ void pgemm(const float* pp, const float* pW2, float* outp,
                      int mt, int kq, float* S) {
  const int t = threadIdx.x;
  const int m0 = mt * 64, k0 = kq * 64;
  float* Ws = S;           // 64k x 64m = 4096
  float* As = S + 4096;    // 32b x 68  = 2176
  for (int i = t; i < 1024; i += 256) {
    int r = i >> 4, q = i & 15;
    *(float4*)&Ws[r * 64 + q * 4] = *(const float4*)(pW2 + (size_t)(k0 + r) * 6144 + m0 + q * 4);
  }
  for (int i = t; i < 512; i += 256) {
    int b = i >> 4, q = i & 15;
    *(float4*)&As[b * 68 + q * 4] = *(const float4*)(pp + (size_t)b * 256 + k0 + q * 4);
  }
  __syncthreads();
  const int mf = t & 15, b0 = (t >> 4) * 2;
  float4 a0 = make_float4(0.f, 0.f, 0.f, 0.f), a1 = a0;
  const float* ar0 = As + b0 * 68;
  const float* ar1 = ar0 + 68;
#pragma unroll 8
  for (int k = 0; k < 64; ++k) {
    float4 wv = *(const float4*)&Ws[k * 64 + mf * 4];
    fma4(a0, ar0[k], wv);
    fma4(a1, ar1[k], wv);
  }
  float* op = outp + (size_t)b0 * 6144 + m0 + mf * 4;
  *(float4*)op = a0;
  *(float4*)(op + 6144) = a1;
  __syncthreads();
}

__global__ __launch_bounds__(256, 2) void mega(
    const float* __restrict__ x, const float* __restrict__ gW1, const float* __restrict__ gb1,
    const float* __restrict__ g1g, const float* __restrict__ g1b,
    const float* __restrict__ gW2, const float* __restrict__ gb2,
    const float* __restrict__ g2g, const float* __restrict__ g2b,
    const float* __restrict__ gW3, const float* __restrict__ gb3,
    const float* __restrict__ protos, const float* __restrict__ temp,
    const float* __restrict__ eW1, const float* __restrict__ eb1,
    const float* __restrict__ eW2, const float* __restrict__ eb2,
    const float* __restrict__ fW1, const float* __restrict__ fb1,
    const float* __restrict__ flg, const float* __restrict__ flb,
    const float* __restrict__ fW2, const float* __restrict__ fb2,
    const float* __restrict__ lng, const float* __restrict__ lnb,
    const float* __restrict__ pW1, const float* __restrict__ pb1,
    const float* __restrict__ plg, const float* __restrict__ plb,
    const float* __restrict__ pW2, const float* __restrict__ pb2,
    const float* __restrict__ ong, const float* __restrict__ onb,
    float* __restrict__ ws, unsigned* __restrict__ bar,
    float* __restrict__ outp) {
  __shared__ __align__(16) float S[16512];  // 66,048 B phase-union
  __shared__ float red4s[4];
  __shared__ float aux[912];  // P4: hb[512] emb[128] embp[256] wl[8] d2s[8]

  float* part   = ws;                // region0: part(P0-P1)/epart(P2-P4)/fpart(P11-P12)
  float* epart  = ws;
  float* fpart  = ws;
  float* he_all = ws + 2097152;      // 131072
  float* h1     = ws + 2228224;      // 16384
  float* h2     = h1 + 16384;
  float* zp     = h2 + 16384;        // 262144 (16 kq x 32 x 512)
  float* fused  = zp + 262144;
  float* f1     = fused + 16384;
  float* lastv  = f1 + 16384;
  float* pp     = lastv + 16384;     // 8192

  const int bid = blockIdx.x;
  const int t = threadIdx.x;
  unsigned phase = 0;

  // ---- P0: gemm1 partials: part[ks][b][m] ----
  {
    const int mt = bid & 3, ks = bid >> 2;
    const int m0 = mt * 128, k0 = ks * 256;
    float* As = S;          // 32 x 260
    float* Ws = S + 8320;   // 64 x 128
    for (int i = t; i < 2048; i += 256) {
      int b = i >> 6, q = i & 63;
      *(float4*)&As[b * 260 + q * 4] = *(const float4*)(x + (size_t)b * DIMK + k0 + q * 4);
    }
    const float* Wp = gW1 + (size_t)k0 * 512 + m0;
    float4 wreg[8];
#pragma unroll
    for (int j = 0; j < 8; ++j) {
      int i = t + j * 256, r = i >> 5, q = i & 31;
      wreg[j] = *(const float4*)(Wp + (size_t)r * 512 + q * 4);
    }
    const int mf = t & 31, bg = t >> 5;
    const int b0 = bg * 4;
    float4 acc[4];
#pragma unroll
    for (int j = 0; j < 4; ++j) acc[j] = make_float4(0.f, 0.f, 0.f, 0.f);
    const float* a0 = &As[b0 * 260];
    for (int s = 0; s < 4; ++s) {
      __syncthreads();
#pragma unroll
      for (int j = 0; j < 8; ++j) {
        int i = t + j * 256, r = i >> 5, q = i & 31;
        *(float4*)&Ws[r * 128 + q * 4] = wreg[j];
      }
      __syncthreads();
      if (s < 3) {
        const float* Wn = Wp + (size_t)(s + 1) * 64 * 512;
#pragma unroll
        for (int j = 0; j < 8; ++j) {
          int i = t + j * 256, r = i >> 5, q = i & 31;
          wreg[j] = *(const float4*)(Wn + (size_t)r * 512 + q * 4);
        }
      }
      const float* ab = a0 + s * 64;
#pragma unroll 8
      for (int k = 0; k < 64; ++k) {
        float4 wv = *(const float4*)&Ws[k * 128 + mf * 4];
        fma4(acc[0], ab[k], wv);
        fma4(acc[1], ab[260 + k], wv);
        fma4(acc[2], ab[520 + k], wv);
        fma4(acc[3], ab[780 + k], wv);
      }
    }
    float* op = part + ((size_t)ks * 32 + b0) * 512 + m0 + mf * 4;
#pragma unroll
    for (int j = 0; j < 4; ++j) *(float4*)(op + (size_t)j * 512) = acc[j];
  }
  gsync(bar, ++phase * NB);

  // ---- P1: gred_ln -> h1 (32 blk) | he_k (16 blk) ----
  if (bid < 32) {
    redln512(part, gb1, g1g, g1b, h1, bid, 128, 1, red4s);
  } else if (bid < 48) {
    const int e = (bid - 32) >> 1, hs = (bid - 32) & 1;
    float* xs = S;          // 32 x 64
    float* Ws = S + 2048;   // 32 x 256
    for (int i = t; i < 512; i += 256) {
      int b = i >> 4, q = i & 15;
      *(float4*)&xs[b * 64 + q * 4] = *(const float4*)(x + (size_t)b * DIMK + 32704 + q * 4);
    }
    float acc[32];
#pragma unroll
    for (int b = 0; b < 32; ++b) acc[b] = 0.f;
    for (int half = 0; half < 2; ++half) {
      __syncthreads();
      const float* w1 = eW1 + (size_t)e * 32768 + (size_t)(half * 32) * 512 + hs * 256;
      for (int i = t; i < 2048; i += 256) {
        int r = i >> 6, q = i & 63;
        *(float4*)&Ws[r * 256 + q * 4] = *(const float4*)(w1 + (size_t)r * 512 + q * 4);
      }
      __syncthreads();
#pragma unroll 4
      for (int k = 0; k < 32; ++k) {
        float wk = Ws[k * 256 + t];
#pragma unroll
        for (int b = 0; b < 32; ++b) acc[b] += xs[b * 64 + half * 32 + k] * wk;
      }
    }
    float bb = eb1[e * 512 + hs * 256 + t];
    for (int b = 0; b < 32; ++b)
      he_all[((size_t)e * 32 + b) * 512 + hs * 256 + t] = fmaxf(acc[b] + bb, 0.f);
  }
  gsync(bar, ++phase * NB);

  // ---- P2: h1@gW2 partials (256 blk) | he_all@eW2 -> epart (256 blk) ----
  if (bid < 256) {
    sgemm32(h1, 512, gW2, 512, zp, bid & 15, bid >> 4, S);
  } else {
    const int v = bid - 256;
    const int kq = v >> 6, e = (v >> 3) & 7, mt = v & 7;
    egemm(he_all + (size_t)e * 16384, eW2 + (size_t)e * 262144,
          epart + ((size_t)(kq * 8 + e) * 32) * 512, mt, kq, S);
  }
  gsync(bar, ++phase * NB);

  // ---- P3: red_ln -> h2 ----
  if (bid < 32) redln512(zp, gb2, g2g, g2b, h2, bid, 16, 1, red4s);
  gsync(bar, ++phase * NB);

  // ---- P4: per-b emb -> gate -> ffuse (32 blk) ----
  if (bid < 32) {
    const int b = bid;
    float* hb = aux;          // 512
    float* emb = aux + 512;   // 128
    float* embp = aux + 640;  // 256
    float* wl = aux + 896;    // 8
    float* d2s = aux + 904;   // 8
    hb[t] = h2[b * 512 + t];
    hb[t + 256] = h2[b * 512 + t + 256];
    __syncthreads();
    {
      const int m = t & 127, kh = t >> 7;
      float c = 0.f;
      const float* w3 = gW3 + m;
#pragma unroll 8
      for (int k = kh * 256; k < kh * 256 + 256; ++k) c += hb[k] * w3[(size_t)k * 128];
      embp[kh * 128 + m] = c;
    }
    __syncthreads();
    if (t < 128) emb[t] = gb3[t] + embp[t] + embp[128 + t];
    __syncthreads();
    for (int e = 0; e < 8; ++e) {
      float dd = 0.f;
      if (t < 128) { float z = emb[t] - protos[e * 128 + t]; dd = z * z; }
      float s = bsum(dd, red4s);
      if (t == 0) d2s[e] = s;
    }
    __syncthreads();
    if (t == 0) {
      float tt = fminf(fmaxf(temp[0], 0.1f), 5.0f);
      float lg[8], mx = -1e30f;
#pragma unroll
      for (int e = 0; e < 8; ++e) {
        float dist = sqrtf(fmaxf(d2s[e], 1e-12f));
        lg[e] = -dist / tt;
        mx = fmaxf(mx, lg[e]);
      }
      float se = 0.f;
#pragma unroll
      for (int e = 0; e < 8; ++e) { lg[e] = expf(lg[e] - mx); se += lg[e]; }
#pragma unroll
      for (int e = 0; e < 8; ++e) wl[e] = lg[e] / se;
    }
    __syncthreads();
    float a0 = 0.f, a1 = 0.f;
#pragma unroll
    for (int e = 0; e < 8; ++e) {
      float s0 = eb2[e * 512 + t], s1 = eb2[e * 512 + t + 256];
#pragma unroll
      for (int kq = 0; kq < 4; ++kq) {
        const float* pe = epart + ((size_t)(kq * 8 + e) * 32 + b) * 512;
        s0 += pe[t]; s1 += pe[t + 256];
      }
      a0 += wl[e] * s0; a1 += wl[e] * s1;
    }
    fused[b * 512 + t] = a0;
    fused[b * 512 + t + 256] = a1;
  }
  gsync(bar, ++phase * NB);

  // ---- P5: fused@fW1 partials ----
  if (bid < 256) sgemm32(fused, 512, fW1, 512, zp, bid & 15, bid >> 4, S);
  gsync(bar, ++phase * NB);
  // ---- P6: red_ln -> f1 ----
  if (bid < 32) redln512(zp, fb1, flg, flb, f1, bid, 16, 1, red4s);
  gsync(bar, ++phase * NB);
  // ---- P7: f1@fW2 partials ----
  if (bid < 256) sgemm32(f1, 512, fW2, 512, zp, bid & 15, bid >> 4, S);
  gsync(bar, ++phase * NB);
  // ---- P8: red_ln -> lastv (no relu) ----
  if (bid < 32) redln512(zp, fb2, lng, lnb, lastv, bid, 16, 0, red4s);
  gsync(bar, ++phase * NB);
  // ---- P9: lastv@pW1 partials (M=256) ----
  if (bid < 128) sgemm32(lastv, 512, pW1, 256, zp, bid & 7, bid >> 3, S);
  gsync(bar, ++phase * NB);
  // ---- P10: red_ln -> pp ----
  if (bid < 32) redln256(zp, pb1, plg, plb, pp, bid, 16, 1, red4s);
  gsync(bar, ++phase * NB);
  // ---- P11: pp@pW2 -> fpart (384 blk) ----
  if (bid < 384) {
    const int kq = bid / 96, mt = bid % 96;
    pgemm(pp, pW2, fpart + (size_t)(kq * 32) * 6144, mt, kq, S);
  }
  gsync(bar, ++phase * NB);
  // ---- P12: final reduce + LN over O=64 ----
  for (int r0 = bid * 4 + (t >> 6); r0 < 3072; r0 += NB * 4) {
    const int lane = t & 63;
    const int b = r0 / 96, pi = r0 % 96;
    const int m = pi * 64 + lane;
    float a = pb2[m];
#pragma unroll
    for (int kq = 0; kq < 4; ++kq) a += fpart[((size_t)kq * 32 + b) * 6144 + m];
    float s = a;
    for (int o = 1; o < 64; o <<= 1) s += __shfl_xor(s, o);
    float mean = s * (1.f / 64.f);
    float d = a - mean;
    float q = d * d;
    for (int o = 1; o < 64; o <<= 1) q += __shfl_xor(q, o);
    float rr = rsqrtf(q * (1.f / 64.f) + 1e-5f);
    outp[(size_t)r0 * 64 + lane] = d * rr * ong[lane] + onb[lane];
  }
}

extern "C" void kernel_launch(void* const* d_in, const int* in_sizes, int n_in,
                              void* d_out, int out_size, void* d_ws, size_t ws_size,
                              hipStream_t stream) {
  (void)in_sizes; (void)n_in; (void)out_size; (void)ws_size;
  const float* x      = (const float*)d_in[0];
  const float* gW1    = (const float*)d_in[1];
  const float* gb1    = (const float*)d_in[2];
  const float* gln1_g = (const float*)d_in[3];
  const float* gln1_b = (const float*)d_in[4];
  const float* gW2    = (const float*)d_in[5];
  const float* gb2    = (const float*)d_in[6];
  const float* gln2_g = (const float*)d_in[7];
  const float* gln2_b = (const float*)d_in[8];
  const float* gW3    = (const float*)d_in[9];
  const float* gb3    = (const float*)d_in[10];
  const float* protos = (const float*)d_in[11];
  const float* temp   = (const float*)d_in[12];
  const float* eW1    = (const float*)d_in[13];
  const float* eb1    = (const float*)d_in[14];
  const float* eW2    = (const float*)d_in[15];
  const float* eb2    = (const float*)d_in[16];
  const float* fW1    = (const float*)d_in[17];
  const float* fb1    = (const float*)d_in[18];
  const float* fln_g  = (const float*)d_in[19];
  const float* fln_b  = (const float*)d_in[20];
  const float* fW2    = (const float*)d_in[21];
  const float* fb2    = (const float*)d_in[22];
  const float* ln_g   = (const float*)d_in[23];
  const float* ln_b   = (const float*)d_in[24];
  const float* pW1    = (const float*)d_in[25];
  const float* pb1    = (const float*)d_in[26];
  const float* pln_g  = (const float*)d_in[27];
  const float* pln_b  = (const float*)d_in[28];
  const float* pW2    = (const float*)d_in[29];
  const float* pb2    = (const float*)d_in[30];
  const float* on_g   = (const float*)d_in[31];
  const float* on_b   = (const float*)d_in[32];
  float* out = (float*)d_out;

  float* ws = (float*)d_ws;
  unsigned* bar = (unsigned*)(ws + 2580608);  // 64B-aligned, past all buffers

  hipMemsetAsync((void*)bar, 0, 64, stream);
  mega<<<NB, 256, 0, stream>>>(x, gW1, gb1, gln1_g, gln1_b, gW2, gb2, gln2_g, gln2_b,
                               gW3, gb3, protos, temp, eW1, eb1, eW2, eb2,
                               fW1, fb1, fln_g, fln_b, fW2, fb2, ln_g, ln_b,
                               pW1, pb1, pln_g, pln_b, pW2, pb2, on_g, on_b,
                               ws, bar, out);
}

// Round 6
// 618.162 us; speedup vs baseline: 1.8688x; 1.8688x over previous
//
#include <hip/hip_runtime.h>
#include <math.h>

// Shapes: B=32, S=512, I=64, H=512, E=8, P=96, O=64, EM=512; D = S*I = 32768.
#define DIMK 32768
#define NB 512  // persistent grid: 2 blocks/CU x 256 CUs (LDS 70KB -> 2/CU)

__device__ __forceinline__ void fma4(float4& a, float s, const float4 w) {
  a.x += s * w.x; a.y += s * w.y; a.z += s * w.z; a.w += s * w.w;
}

// Tree grid barrier. bar layout (uints, 64B lanes): [0]=flag, [16+16*g]=group g
// counter (g<8), [16*9]=root. Arrivals are ACQ_REL RMWs (2-3 cache ops per
// block per phase); the spin polls the flag with RELAXED loads (LLC-served,
// NO per-poll invalidate — round-5's fatal flaw), one __threadfence on exit.
__device__ __forceinline__ void gsync(unsigned* bar, unsigned phase) {
  __syncthreads();
  if (threadIdx.x == 0) {
    __threadfence();  // release our global writes
    const int g = blockIdx.x & 7;
    unsigned old = __hip_atomic_fetch_add(&bar[16 + 16 * g], 1u,
                                          __ATOMIC_ACQ_REL, __HIP_MEMORY_SCOPE_AGENT);
    if (old == phase * 64u - 1u) {  // last of this group's 64 arrivals
      unsigned r = __hip_atomic_fetch_add(&bar[16 * 9], 1u,
                                          __ATOMIC_ACQ_REL, __HIP_MEMORY_SCOPE_AGENT);
      if (r == phase * 8u - 1u)  // last group: publish
        __hip_atomic_store(&bar[0], phase, __ATOMIC_RELEASE, __HIP_MEMORY_SCOPE_AGENT);
    }
    long guard = 0;
    while (__hip_atomic_load(&bar[0], __ATOMIC_RELAXED, __HIP_MEMORY_SCOPE_AGENT) < phase) {
      __builtin_amdgcn_s_sleep(8);
      if (++guard > 2000000) break;  // degrade to wrong-answer instead of hang
    }
    __threadfence();  // acquire once: see producers' data
  }
  __syncthreads();
}

// block sum over 256 threads
__device__ __forceinline__ float bsum(float v, volatile float* r4) {
  for (int o = 1; o < 64; o <<= 1) v += __shfl_xor(v, o);
  const int w = threadIdx.x >> 6;
  __syncthreads();
  if ((threadIdx.x & 63) == 0) r4[w] = v;
  __syncthreads();
  return r4[0] + r4[1] + r4[2] + r4[3];
}

// LN over 512 cols of sum_{kq<nq} zp[(kq*32+b)*512+m] + bias -> global out
__device__ void redln512(const float* zp, const float* bias, const float* g,
                         const float* bt, float* outp, int b, int nq, int relu,
                         volatile float* r4) {
  const int t = threadIdx.x;
  float a0 = bias[t], a1 = bias[t + 256];
  const float* p = zp + (size_t)b * 512;
#pragma unroll 8
  for (int kq = 0; kq < nq; ++kq) { a0 += p[t]; a1 += p[t + 256]; p += 512 * 32; }
  float mean = bsum(a0 + a1, r4) * (1.f / 512.f);
  float d0 = a0 - mean, d1 = a1 - mean;
  float var = bsum(d0 * d0 + d1 * d1, r4) * (1.f / 512.f);
  float rr = rsqrtf(var + 1e-5f);
  float v0 = d0 * rr * g[t] + bt[t];
  float v1 = d1 * rr * g[t + 256] + bt[t + 256];
  outp[b * 512 + t] = relu ? fmaxf(v0, 0.f) : v0;
  outp[b * 512 + t + 256] = relu ? fmaxf(v1, 0.f) : v1;
}

// same but result stays in LDS row buffer hb[512]
__device__ void redln512_lds(const float* zp, const float* bias, const float* g,
                             const float* bt, float* hb, int b, int nq, int relu,
                             volatile float* r4) {
  const int t = threadIdx.x;
  float a0 = bias[t], a1 = bias[t + 256];
  const float* p = zp + (size_t)b * 512;
#pragma unroll 8
  for (int kq = 0; kq < nq; ++kq) { a0 += p[t]; a1 += p[t + 256]; p += 512 * 32; }
  float mean = bsum(a0 + a1, r4) * (1.f / 512.f);
  float d0 = a0 - mean, d1 = a1 - mean;
  float var = bsum(d0 * d0 + d1 * d1, r4) * (1.f / 512.f);
  float rr = rsqrtf(var + 1e-5f);
  float v0 = d0 * rr * g[t] + bt[t];
  float v1 = d1 * rr * g[t + 256] + bt[t + 256];
  hb[t] = relu ? fmaxf(v0, 0.f) : v0;
  hb[t + 256] = relu ? fmaxf(v1, 0.f) : v1;
  __syncthreads();
}

// small GEMM tile: 32 b x 32 m x 32 k, LDS-staged. outp[(kq*32+b)*M + m]
__device__ void sgemm32(const float* A, int aRow, const float* W, int M,
                        float* outp, int mt, int kq, float* S) {
  const int t = threadIdx.x;
  const int m0 = mt * 32, k0 = kq * 32;
  float* Ws = S;           // 32k x 32m
  float* As = S + 1024;    // 32b x 36
  {
    int r = t >> 3, q = t & 7;
    *(float4*)&Ws[r * 32 + q * 4] = *(const float4*)(W + (size_t)(k0 + r) * M + m0 + q * 4);
    *(float4*)&As[r * 36 + q * 4] = *(const float4*)(A + (size_t)r * aRow + k0 + q * 4);
  }
  __syncthreads();
  const int b = t >> 3, mf = t & 7;
  float4 acc = make_float4(0.f, 0.f, 0.f, 0.f);
#pragma unroll
  for (int k = 0; k < 32; ++k)
    fma4(acc, As[b * 36 + k], *(const float4*)&Ws[k * 32 + mf * 4]);
  *(float4*)(outp + ((size_t)kq * 32 + b) * M + m0 + mf * 4) = acc;
  __syncthreads();
}

// expert GEMM tile: 32 b x 64 m x 128 k. outp base pre-offset to [b*512+m]
__device__ void egemm(const float* A, const float* W, float* outp,
                      int mt, int kq, float* S) {
  const int t = threadIdx.x;
  const int m0 = mt * 64, k0 = kq * 128;
  float* Ws = S;           // 128k x 64m
  float* As = S + 8192;    // 32b x 132
  for (int i = t; i < 2048; i += 256) {
    int r = i >> 4, q = i & 15;
    *(float4*)&Ws[r * 64 + q * 4] = *(const float4*)(W + (size_t)(k0 + r) * 512 + m0 + q * 4);
  }
  for (int i = t; i < 1024; i += 256) {
    int b = i >> 5, q = i & 31;
    *(float4*)&As[b * 132 + q * 4] = *(const float4*)(A + (size_t)b * 512 + k0 + q * 4);
  }
  __syncthreads();
  const int mf = t & 15, b0 = (t >> 4) * 2;
  float4 a0 = make_float4(0.f, 0.f, 0.f, 0.f), a1 = a0;
  const float* ar0 = As + b0 * 132;
  const float* ar1 = ar0 + 132;
#pragma unroll 4
  for (int k = 0; k < 128; ++k) {
    float4 wv = *(const float4*)&Ws[k * 64 + mf * 4];
    fma4(a0, ar0[k], wv);
    fma4(a1, ar1[k], wv);
  }
  float* op = outp + (size_t)b0 * 512 + m0 + mf * 4;
  *(float4*)op = a0;
  *(float4*)(op + 512) = a1;
  __syncthreads();
}

// pW2 GEMM tile: 32 b x 64 m x 64 k, M=6144. outp[(kq*32+b)*6144 + m]
__device__ void pgemm(const float* pp, const float* pW2, float* outp,
                      int mt, int kq, float* S) {
  const int t = threadIdx.x;
  const int m0 = mt * 64, k0 = kq * 64;
  float* Ws = S;           // 64k x 64m
  float* As = S + 4096;    // 32b x 68
  for (int i = t; i < 1024; i += 256) {
    int r = i >> 4, q = i & 15;
    *(float4*)&Ws[r * 64 + q * 4] = *(const float4*)(pW2 + (size_t)(k0 + r) * 6144 + m0 + q * 4);
  }
  for (int i = t; i < 512; i += 256) {
    int b = i >> 4, q = i & 15;
    *(float4*)&As[b * 68 + q * 4] = *(const float4*)(pp + (size_t)b * 256 + k0 + q * 4);
  }
  __syncthreads();
  const int mf = t & 15, b0 = (t >> 4) * 2;
  float4 a0 = make_float4(0.f, 0.f, 0.f, 0.f), a1 = a0;
  const float* ar0 = As + b0 * 68;
  const float* ar1 = ar0 + 68;
#pragma unroll 8
  for (int k = 0; k < 64; ++k) {
    float4 wv = *(const float4*)&Ws[k * 64 + mf * 4];
    fma4(a0, ar0[k], wv);
    fma4(a1, ar1[k], wv);
  }
  float* op = outp + (size_t)b0 * 6144 + m0 + mf * 4;
  *(float4*)op = a0;
  *(float4*)(op + 6144) = a1;
  __syncthreads();
}

__global__ __launch_bounds__(256, 2) void mega(
    const float* __restrict__ x, const float* __restrict__ gW1, const float* __restrict__ gb1,
    const float* __restrict__ g1g, const float* __restrict__ g1b,
    const float* __restrict__ gW2, const float* __restrict__ gb2,
    const float* __restrict__ g2g, const float* __restrict__ g2b,
    const float* __restrict__ gW3, const float* __restrict__ gb3,
    const float* __restrict__ protos, const float* __restrict__ temp,
    const float* __restrict__ eW1, const float* __restrict__ eb1,
    const float* __restrict__ eW2, const float* __restrict__ eb2,
    const float* __restrict__ fW1, const float* __restrict__ fb1,
    const float* __restrict__ flg, const float* __restrict__ flb,
    const float* __restrict__ fW2, const float* __restrict__ fb2,
    const float* __restrict__ lng, const float* __restrict__ lnb,
    const float* __restrict__ pW1, const float* __restrict__ pb1,
    const float* __restrict__ plg, const float* __restrict__ plb,
    const float* __restrict__ pW2, const float* __restrict__ pb2,
    const float* __restrict__ ong, const float* __restrict__ onb,
    float* __restrict__ ws, unsigned* __restrict__ bar,
    float* __restrict__ outp) {
  __shared__ __align__(16) float S[16512];  // 66,048 B phase-union
  __shared__ float red4s[4];
  __shared__ float aux[912];

  float* part   = ws;                // region0: part(P0-P1)/epart(P2-P3)/fpart(P8-P9)
  float* epart  = ws;
  float* fpart  = ws;
  float* he_all = ws + 2097152;      // 131072
  float* h1     = ws + 2228224;      // 16384
  float* zp     = h1 + 32768;        // 262144 (16 kq x 32 x 512)
  float* fused  = zp + 262144;
  float* f1     = fused + 16384;
  float* pp     = f1 + 32768;        // 8192

  const int bid = blockIdx.x;
  const int t = threadIdx.x;
  unsigned phase = 0;

  // ---- P0: gemm1 partials: part[ks][b][m] ----
  {
    const int mt = bid & 3, ks = bid >> 2;
    const int m0 = mt * 128, k0 = ks * 256;
    float* As = S;          // 32 x 260
    float* Ws = S + 8320;   // 64 x 128
    for (int i = t; i < 2048; i += 256) {
      int b = i >> 6, q = i & 63;
      *(float4*)&As[b * 260 + q * 4] = *(const float4*)(x + (size_t)b * DIMK + k0 + q * 4);
    }
    const float* Wp = gW1 + (size_t)k0 * 512 + m0;
    float4 wreg[8];
#pragma unroll
    for (int j = 0; j < 8; ++j) {
      int i = t + j * 256, r = i >> 5, q = i & 31;
      wreg[j] = *(const float4*)(Wp + (size_t)r * 512 + q * 4);
    }
    const int mf = t & 31, bg = t >> 5;
    const int b0 = bg * 4;
    float4 acc[4];
#pragma unroll
    for (int j = 0; j < 4; ++j) acc[j] = make_float4(0.f, 0.f, 0.f, 0.f);
    const float* a0 = &S[b0 * 260];
    for (int s = 0; s < 4; ++s) {
      __syncthreads();
#pragma unroll
      for (int j = 0; j < 8; ++j) {
        int i = t + j * 256, r = i >> 5, q = i & 31;
        *(float4*)&Ws[r * 128 + q * 4] = wreg[j];
      }
      __syncthreads();
      if (s < 3) {
        const float* Wn = Wp + (size_t)(s + 1) * 64 * 512;
#pragma unroll
        for (int j = 0; j < 8; ++j) {
          int i = t + j * 256, r = i >> 5, q = i & 31;
          wreg[j] = *(const float4*)(Wn + (size_t)r * 512 + q * 4);
        }
      }
      const float* ab = a0 + s * 64;
#pragma unroll 8
      for (int k = 0; k < 64; ++k) {
        float4 wv = *(const float4*)&Ws[k * 128 + mf * 4];
        fma4(acc[0], ab[k], wv);
        fma4(acc[1], ab[260 + k], wv);
        fma4(acc[2], ab[520 + k], wv);
        fma4(acc[3], ab[780 + k], wv);
      }
    }
    float* op = part + ((size_t)ks * 32 + b0) * 512 + m0 + mf * 4;
#pragma unroll
    for (int j = 0; j < 4; ++j) *(float4*)(op + (size_t)j * 512) = acc[j];
  }
  gsync(bar, ++phase);

  // ---- P1: gred_ln -> h1 (32 blk) | he_k (16 blk) ----
  if (bid < 32) {
    redln512(part, gb1, g1g, g1b, h1, bid, 128, 1, red4s);
  } else if (bid < 48) {
    const int e = (bid - 32) >> 1, hs = (bid - 32) & 1;
    float* xs = S;          // 32 x 64
    float* Ws = S + 2048;   // 32 x 256
    for (int i = t; i < 512; i += 256) {
      int b = i >> 4, q = i & 15;
      *(float4*)&xs[b * 64 + q * 4] = *(const float4*)(x + (size_t)b * DIMK + 32704 + q * 4);
    }
    float acc[32];
#pragma unroll
    for (int b = 0; b < 32; ++b) acc[b] = 0.f;
    for (int half = 0; half < 2; ++half) {
      __syncthreads();
      const float* w1 = eW1 + (size_t)e * 32768 + (size_t)(half * 32) * 512 + hs * 256;
      for (int i = t; i < 2048; i += 256) {
        int r = i >> 6, q = i & 63;
        *(float4*)&Ws[r * 256 + q * 4] = *(const float4*)(w1 + (size_t)r * 512 + q * 4);
      }
      __syncthreads();
#pragma unroll 4
      for (int k = 0; k < 32; ++k) {
        float wk = Ws[k * 256 + t];
#pragma unroll
        for (int b = 0; b < 32; ++b) acc[b] += xs[b * 64 + half * 32 + k] * wk;
      }
    }
    float bb = eb1[e * 512 + hs * 256 + t];
    for (int b = 0; b < 32; ++b)
      he_all[((size_t)e * 32 + b) * 512 + hs * 256 + t] = fmaxf(acc[b] + bb, 0.f);
  }
  gsync(bar, ++phase);

  // ---- P2: h1@gW2 partials (256 blk) | he_all@eW2 -> epart (256 blk) ----
  if (bid < 256) {
    sgemm32(h1, 512, gW2, 512, zp, bid & 15, bid >> 4, S);
  } else {
    const int v = bid - 256;
    const int kq = v >> 6, e = (v >> 3) & 7, mt = v & 7;
    egemm(he_all + (size_t)e * 16384, eW2 + (size_t)e * 262144,
          epart + ((size_t)(kq * 8 + e) * 32) * 512, mt, kq, S);
  }
  gsync(bar, ++phase);

  // ---- P3: per-b: LN->h2(LDS), emb, gate, ffuse (32 blk) ----
  if (bid < 32) {
    const int b = bid;
    float* hb = aux;          // 512
    float* emb = aux + 512;   // 128
    float* embp = aux + 640;  // 256
    float* wl = aux + 896;    // 8
    float* d2s = aux + 904;   // 8
    redln512_lds(zp, gb2, g2g, g2b, hb, b, 16, 1, red4s);
    {
      const int m = t & 127, kh = t >> 7;
      float c = 0.f;
      const float* w3 = gW3 + m;
#pragma unroll 8
      for (int k = kh * 256; k < kh * 256 + 256; ++k) c += hb[k] * w3[(size_t)k * 128];
      embp[kh * 128 + m] = c;
    }
    __syncthreads();
    if (t < 128) emb[t] = gb3[t] + embp[t] + embp[128 + t];
    __syncthreads();
    for (int e = 0; e < 8; ++e) {
      float dd = 0.f;
      if (t < 128) { float z = emb[t] - protos[e * 128 + t]; dd = z * z; }
      float s = bsum(dd, red4s);
      if (t == 0) d2s[e] = s;
    }
    __syncthreads();
    if (t == 0) {
      float tt = fminf(fmaxf(temp[0], 0.1f), 5.0f);
      float lg[8], mx = -1e30f;
#pragma unroll
      for (int e = 0; e < 8; ++e) {
        float dist = sqrtf(fmaxf(d2s[e], 1e-12f));
        lg[e] = -dist / tt;
        mx = fmaxf(mx, lg[e]);
      }
      float se = 0.f;
#pragma unroll
      for (int e = 0; e < 8; ++e) { lg[e] = expf(lg[e] - mx); se += lg[e]; }
#pragma unroll
      for (int e = 0; e < 8; ++e) wl[e] = lg[e] / se;
    }
    __syncthreads();
    float a0 = 0.f, a1 = 0.f;
#pragma unroll
    for (int e = 0; e < 8; ++e) {
      float s0 = eb2[e * 512 + t], s1 = eb2[e * 512 + t + 256];
#pragma unroll
      for (int kq = 0; kq < 4; ++kq) {
        const float* pe = epart + ((size_t)(kq * 8 + e) * 32 + b) * 512;
        s0 += pe[t]; s1 += pe[t + 256];
      }
      a0 += wl[e] * s0; a1 += wl[e] * s1;
    }
    fused[b * 512 + t] = a0;
    fused[b * 512 + t + 256] = a1;
  }
  gsync(bar, ++phase);

  // ---- P4: fused@fW1 partials ----
  if (bid < 256) sgemm32(fused, 512, fW1, 512, zp, bid & 15, bid >> 4, S);
  gsync(bar, ++phase);
  // ---- P5: red_ln -> f1 ----
  if (bid < 32) redln512(zp, fb1, flg, flb, f1, bid, 16, 1, red4s);
  gsync(bar, ++phase);
  // ---- P6: f1@fW2 partials ----
  if (bid < 256) sgemm32(f1, 512, fW2, 512, zp, bid & 15, bid >> 4, S);
  gsync(bar, ++phase);
  // ---- P7: per-b: LN->lastv(LDS), pW1 row-GEMM, LN(256) -> pp (32 blk) ----
  if (bid < 32) {
    const int b = bid;
    float* lastr = aux;  // 512
    redln512_lds(zp, fb2, lng, lnb, lastr, b, 16, 0, red4s);
    float c = pb1[t];
#pragma unroll 8
    for (int k = 0; k < 512; ++k) c += lastr[k] * pW1[(size_t)k * 256 + t];
    float mean = bsum(c, red4s) * (1.f / 256.f);
    float d = c - mean;
    float var = bsum(d * d, red4s) * (1.f / 256.f);
    float v = d * rsqrtf(var + 1e-5f) * plg[t] + plb[t];
    pp[b * 256 + t] = fmaxf(v, 0.f);
  }
  gsync(bar, ++phase);
  // ---- P8: pp@pW2 -> fpart (384 blk) ----
  if (bid < 384) {
    const int kq = bid / 96, mt = bid % 96;
    pgemm(pp, pW2, fpart + (size_t)(kq * 32) * 6144, mt, kq, S);
  }
  gsync(bar, ++phase);
  // ---- P9: final reduce + LN over O=64 ----
  for (int r0 = bid * 4 + (t >> 6); r0 < 3072; r0 += NB * 4) {
    const int lane = t & 63;
    const int b = r0 / 96, pi = r0 % 96;
    const int m = pi * 64 + lane;
    float a = pb2[m];
#pragma unroll
    for (int kq = 0; kq < 4; ++kq) a += fpart[((size_t)kq * 32 + b) * 6144 + m];
    float s = a;
    for (int o = 1; o < 64; o <<= 1) s += __shfl_xor(s, o);
    float mean = s * (1.f / 64.f);
    float d = a - mean;
    float q = d * d;
    for (int o = 1; o < 64; o <<= 1) q += __shfl_xor(q, o);
    float rr = rsqrtf(q * (1.f / 64.f) + 1e-5f);
    outp[(size_t)r0 * 64 + lane] = d * rr * ong[lane] + onb[lane];
  }
}

extern "C" void kernel_launch(void* const* d_in, const int* in_sizes, int n_in,
                              void* d_out, int out_size, void* d_ws, size_t ws_size,
                              hipStream_t stream) {
  (void)in_sizes; (void)n_in; (void)out_size; (void)ws_size;
  const float* x      = (const float*)d_in[0];
  const float* gW1    = (const float*)d_in[1];
  const float* gb1    = (const float*)d_in[2];
  const float* gln1_g = (const float*)d_in[3];
  const float* gln1_b = (const float*)d_in[4];
  const float* gW2    = (const float*)d_in[5];
  const float* gb2    = (const float*)d_in[6];
  const float* gln2_g = (const float*)d_in[7];
  const float* gln2_b = (const float*)d_in[8];
  const float* gW3    = (const float*)d_in[9];
  const float* gb3    = (const float*)d_in[10];
  const float* protos = (const float*)d_in[11];
  const float* temp   = (const float*)d_in[12];
  const float* eW1    = (const float*)d_in[13];
  const float* eb1    = (const float*)d_in[14];
  const float* eW2    = (const float*)d_in[15];
  const float* eb2    = (const float*)d_in[16];
  const float* fW1    = (const float*)d_in[17];
  const float* fb1    = (const float*)d_in[18];
  const float* fln_g  = (const float*)d_in[19];
  const float* fln_b  = (const float*)d_in[20];
  const float* fW2    = (const float*)d_in[21];
  const float* fb2    = (const float*)d_in[22];
  const float* ln_g   = (const float*)d_in[23];
  const float* ln_b   = (const float*)d_in[24];
  const float* pW1    = (const float*)d_in[25];
  const float* pb1    = (const float*)d_in[26];
  const float* pln_g  = (const float*)d_in[27];
  const float* pln_b  = (const float*)d_in[28];
  const float* pW2    = (const float*)d_in[29];
  const float* pb2    = (const float*)d_in[30];
  const float* on_g   = (const float*)d_in[31];
  const float* on_b   = (const float*)d_in[32];
  float* out = (float*)d_out;

  float* ws = (float*)d_ws;
  unsigned* bar = (unsigned*)(ws + 2580608);  // past all buffers

  hipMemsetAsync((void*)bar, 0, 1024, stream);
  mega<<<NB, 256, 0, stream>>>(x, gW1, gb1, gln1_g, gln1_b, gW2, gb2, gln2_g, gln2_b,
                               gW3, gb3, protos, temp, eW1, eb1, eW2, eb2,
                               fW1, fb1, fln_g, fln_b, fW2, fb2, ln_g, ln_b,
                               pW1, pb1, pln_g, pln_b, pW2, pb2, on_g, on_b,
                               ws, bar, out);
}

// Round 7
// 358.155 us; speedup vs baseline: 3.2254x; 1.7260x over previous
//
#include <hip/hip_runtime.h>
#include <math.h>

// Shapes: B=32, S=512, I=64, H=512, E=8, P=96, O=64, EM=512; D = S*I = 32768.
#define DIMK 32768

__device__ __forceinline__ void fma4(float4& a, float s, const float4 w) {
  a.x += s * w.x; a.y += s * w.y; a.z += s * w.z; a.w += s * w.w;
}

// block sum over 512 threads (8 waves)
__device__ __forceinline__ float bsum8(float v, volatile float* r8) {
  for (int o = 1; o < 64; o <<= 1) v += __shfl_xor(v, o);
  const int w = threadIdx.x >> 6;
  __syncthreads();
  if ((threadIdx.x & 63) == 0) r8[w] = v;
  __syncthreads();
  float s = 0.f;
#pragma unroll
  for (int i = 0; i < 8; ++i) s += r8[i];
  return s;
}

// ---------------------------------------------------------------------------
// K1: bid<512: gemm1 tile (exact round-4 code, 46 µs proven);
//     bid>=512: he_all[e][b][h] = relu(x_last @ eW1[e] + eb1[e])  (16 blocks).
__global__ __launch_bounds__(256) void k1_gemm1_he(const float* __restrict__ x,
                                                   const float* __restrict__ gW1,
                                                   const float* __restrict__ eW1,
                                                   const float* __restrict__ eb1,
                                                   float* __restrict__ part,
                                                   float* __restrict__ he_all) {
  __shared__ __align__(16) float S[18432];  // gemm1: 16512 fl; he: 18432 fl (73.7 KB)
  const int t = threadIdx.x;
  if (blockIdx.x < 512) {
    const int mt = blockIdx.x & 3, ks = blockIdx.x >> 2;
    const int m0 = mt * 128, k0 = ks * 256;
    float* As = S;          // 32 x 260
    float* Ws = S + 8320;   // 64 x 128
    for (int i = t; i < 2048; i += 256) {
      int b = i >> 6, q = i & 63;
      *(float4*)&As[b * 260 + q * 4] = *(const float4*)(x + (size_t)b * DIMK + k0 + q * 4);
    }
    const float* Wp = gW1 + (size_t)k0 * 512 + m0;
    float4 wreg[8];
#pragma unroll
    for (int j = 0; j < 8; ++j) {
      int i = t + j * 256, r = i >> 5, q = i & 31;
      wreg[j] = *(const float4*)(Wp + (size_t)r * 512 + q * 4);
    }
    const int mf = t & 31, bg = t >> 5;
    const int b0 = bg * 4;
    float4 acc[4];
#pragma unroll
    for (int j = 0; j < 4; ++j) acc[j] = make_float4(0.f, 0.f, 0.f, 0.f);
    const float* a0 = &As[b0 * 260];
    for (int s = 0; s < 4; ++s) {
      __syncthreads();
#pragma unroll
      for (int j = 0; j < 8; ++j) {
        int i = t + j * 256, r = i >> 5, q = i & 31;
        *(float4*)&Ws[r * 128 + q * 4] = wreg[j];
      }
      __syncthreads();
      if (s < 3) {
        const float* Wn = Wp + (size_t)(s + 1) * 64 * 512;
#pragma unroll
        for (int j = 0; j < 8; ++j) {
          int i = t + j * 256, r = i >> 5, q = i & 31;
          wreg[j] = *(const float4*)(Wn + (size_t)r * 512 + q * 4);
        }
      }
      const float* ab = a0 + s * 64;
#pragma unroll 8
      for (int k = 0; k < 64; ++k) {
        float4 wv = *(const float4*)&Ws[k * 128 + mf * 4];
        fma4(acc[0], ab[k], wv);
        fma4(acc[1], ab[260 + k], wv);
        fma4(acc[2], ab[520 + k], wv);
        fma4(acc[3], ab[780 + k], wv);
      }
    }
    float* op = part + ((size_t)ks * 32 + b0) * 512 + m0 + mf * 4;
#pragma unroll
    for (int j = 0; j < 4; ++j) *(float4*)(op + (size_t)j * 512) = acc[j];
  } else {
    const int v = blockIdx.x - 512;
    const int e = v >> 1, hs = v & 1;
    float* xs = S;          // 32 x 64
    float* Ws = S + 2048;   // 64 x 256
    for (int i = t; i < 512; i += 256) {
      int b = i >> 4, q = i & 15;
      *(float4*)&xs[b * 64 + q * 4] = *(const float4*)(x + (size_t)b * DIMK + 32704 + q * 4);
    }
    const float* w1 = eW1 + (size_t)e * 32768 + hs * 256;
    for (int i = t; i < 4096; i += 256) {
      int r = i >> 6, q = i & 63;
      *(float4*)&Ws[r * 256 + q * 4] = *(const float4*)(w1 + (size_t)r * 512 + q * 4);
    }
    __syncthreads();
    float acc[32];
#pragma unroll
    for (int b = 0; b < 32; ++b) acc[b] = 0.f;
#pragma unroll 4
    for (int k = 0; k < 64; ++k) {
      float wk = Ws[k * 256 + t];
#pragma unroll
      for (int b = 0; b < 32; ++b) acc[b] += xs[b * 64 + k] * wk;
    }
    float bb = eb1[e * 512 + hs * 256 + t];
    for (int b = 0; b < 32; ++b)
      he_all[((size_t)e * 32 + b) * 512 + hs * 256 + t] = fmaxf(acc[b] + bb, 0.f);
  }
}

// ---------------------------------------------------------------------------
// K2: bid<32 (b=bid): [reduce part + LN -> h1(LDS)] -> gW2 GEMM -> LN ->
//     gW3 -> gate softmax -> wgt.   bid>=32: eW2 GEMM (full K) -> eo.
// block 512.
__global__ __launch_bounds__(512) void k2_gtail_eg(const float* __restrict__ part,
                                                   const float* __restrict__ gb1,
                                                   const float* __restrict__ g1g, const float* __restrict__ g1b,
                                                   const float* __restrict__ gW2, const float* __restrict__ gb2,
                                                   const float* __restrict__ g2g, const float* __restrict__ g2b,
                                                   const float* __restrict__ gW3, const float* __restrict__ gb3,
                                                   const float* __restrict__ protos, const float* __restrict__ temp,
                                                   const float* __restrict__ he_all, const float* __restrict__ eW2,
                                                   float* __restrict__ wgt, float* __restrict__ eo) {
  __shared__ __align__(16) float S[16512];  // e-blocks: As 32x260 + Ws 128x64
  __shared__ float hb[512], h2b[512], embp[512], embs[128], d2s[8];
  __shared__ float r8[8];
  const int t = threadIdx.x;
  if (blockIdx.x < 32) {
    const int b = blockIdx.x;
    // reduce 128 k-split partials + LN -> hb
    float a = gb1[t];
    const float* p0 = part + (size_t)b * 512 + t;
#pragma unroll 8
    for (int ks = 0; ks < 128; ++ks) a += p0[(size_t)ks * 16384];
    float mean = bsum8(a, r8) * (1.f / 512.f);
    float d = a - mean;
    float var = bsum8(d * d, r8) * (1.f / 512.f);
    hb[t] = fmaxf(d * rsqrtf(var + 1e-5f) * g1g[t] + g1b[t], 0.f);
    __syncthreads();
    // gW2 row-GEMM (coalesced across t) + LN -> h2b
    float y = gb2[t];
    {
      const float* wp = gW2 + t;
#pragma unroll 8
      for (int k = 0; k < 512; ++k) y += hb[k] * wp[(size_t)k * 512];
    }
    mean = bsum8(y, r8) * (1.f / 512.f);
    d = y - mean;
    var = bsum8(d * d, r8) * (1.f / 512.f);
    h2b[t] = fmaxf(d * rsqrtf(var + 1e-5f) * g2g[t] + g2b[t], 0.f);
    __syncthreads();
    // gW3 (512x128), 4-way k-split over thread halves
    {
      const int kh = t >> 7, m = t & 127;
      float c = 0.f;
      const float* w3 = gW3 + m;
#pragma unroll 8
      for (int k = kh * 128; k < kh * 128 + 128; ++k) c += h2b[k] * w3[(size_t)k * 128];
      embp[t] = c;
    }
    __syncthreads();
    if (t < 128) embs[t] = gb3[t] + embp[t] + embp[128 + t] + embp[256 + t] + embp[384 + t];
    __syncthreads();
    // gate: wave w = expert e
    {
      const int e = t >> 6, l = t & 63;
      float z0 = embs[l] - protos[e * 128 + l];
      float z1 = embs[l + 64] - protos[e * 128 + 64 + l];
      float q = z0 * z0 + z1 * z1;
      for (int o = 1; o < 64; o <<= 1) q += __shfl_xor(q, o);
      if (l == 0) d2s[e] = q;
    }
    __syncthreads();
    if (t == 0) {
      float tt = fminf(fmaxf(temp[0], 0.1f), 5.0f);
      float lg[8], mx = -1e30f;
#pragma unroll
      for (int e = 0; e < 8; ++e) {
        float dist = sqrtf(fmaxf(d2s[e], 1e-12f));
        lg[e] = -dist / tt;
        mx = fmaxf(mx, lg[e]);
      }
      float se = 0.f;
#pragma unroll
      for (int e = 0; e < 8; ++e) { lg[e] = expf(lg[e] - mx); se += lg[e]; }
#pragma unroll
      for (int e = 0; e < 8; ++e) wgt[b * 8 + e] = lg[e] / se;
    }
  } else {
    // expert GEMM: eo[e][b][m0..m0+63] = he_all[e] @ eW2[e][:, m-tile], full K=512
    const int v = blockIdx.x - 32;
    const int e = v >> 3, mt = v & 7;
    const int m0 = mt * 64;
    float* As = S;          // 32 x 260 (one 256-k half)
    float* Ws = S + 8320;   // 128 x 64
    const int mf = t & 15, bg = t >> 4;  // bg = b (0..31)
    float4 acc = make_float4(0.f, 0.f, 0.f, 0.f);
    const float* Ae = he_all + (size_t)e * 16384;
    const float* We = eW2 + (size_t)e * 262144 + m0;
    for (int kh = 0; kh < 2; ++kh) {
      __syncthreads();
      for (int i = t; i < 2048; i += 512) {
        int b = i >> 6, q = i & 63;
        *(float4*)&As[b * 260 + q * 4] =
            *(const float4*)(Ae + (size_t)b * 512 + kh * 256 + q * 4);
      }
      for (int sub = 0; sub < 2; ++sub) {
        __syncthreads();
        const float* wp = We + (size_t)(kh * 256 + sub * 128) * 512;
        for (int i = t; i < 2048; i += 512) {
          int r = i >> 4, q = i & 15;
          *(float4*)&Ws[r * 64 + q * 4] = *(const float4*)(wp + (size_t)r * 512 + q * 4);
        }
        __syncthreads();
        const float* ar = As + bg * 260 + sub * 128;
#pragma unroll 8
        for (int k = 0; k < 128; ++k)
          fma4(acc, ar[k], *(const float4*)&Ws[k * 64 + mf * 4]);
      }
    }
    *(float4*)(eo + ((size_t)e * 32 + bg) * 512 + m0 + mf * 4) = acc;
  }
}

// ---------------------------------------------------------------------------
// K3: per-b f-path: ffuse -> fW1+LN -> fW2+LN -> pW1+LN(256) -> pp. 32 blk x 512.
__global__ __launch_bounds__(512) void k3_fpath(const float* __restrict__ eo,
                                                const float* __restrict__ eb2,
                                                const float* __restrict__ wgt,
                                                const float* __restrict__ fW1, const float* __restrict__ fb1,
                                                const float* __restrict__ flg, const float* __restrict__ flb,
                                                const float* __restrict__ fW2, const float* __restrict__ fb2,
                                                const float* __restrict__ lng, const float* __restrict__ lnb,
                                                const float* __restrict__ pW1, const float* __restrict__ pb1,
                                                const float* __restrict__ plg, const float* __restrict__ plb,
                                                float* __restrict__ pp) {
  __shared__ float rowA[512], pl[512], r8[8], wl8[8];
  const int b = blockIdx.x, t = threadIdx.x;
  if (t < 8) wl8[t] = wgt[b * 8 + t];
  __syncthreads();
  // ffuse
  {
    float a = 0.f;
#pragma unroll
    for (int e = 0; e < 8; ++e)
      a += wl8[e] * (eo[((size_t)e * 32 + b) * 512 + t] + eb2[e * 512 + t]);
    rowA[t] = a;
  }
  __syncthreads();
  // fW1 + LN + relu
  {
    float y = fb1[t];
    const float* wp = fW1 + t;
#pragma unroll 8
    for (int k = 0; k < 512; ++k) y += rowA[k] * wp[(size_t)k * 512];
    float mean = bsum8(y, r8) * (1.f / 512.f);
    float d = y - mean;
    float var = bsum8(d * d, r8) * (1.f / 512.f);
    float v = d * rsqrtf(var + 1e-5f) * flg[t] + flb[t];
    rowA[t] = fmaxf(v, 0.f);
  }
  __syncthreads();
  // fW2 + LN (no relu)
  {
    float y = fb2[t];
    const float* wp = fW2 + t;
#pragma unroll 8
    for (int k = 0; k < 512; ++k) y += rowA[k] * wp[(size_t)k * 512];
    float mean = bsum8(y, r8) * (1.f / 512.f);
    float d = y - mean;
    float var = bsum8(d * d, r8) * (1.f / 512.f);
    rowA[t] = d * rsqrtf(var + 1e-5f) * lng[t] + lnb[t];
  }
  __syncthreads();
  // pW1 (512x256), 2-way k-split + LN(256) + relu -> pp
  {
    const int half = t >> 8, j = t & 255;
    float c = 0.f;
    const float* wp = pW1 + j;
#pragma unroll 8
    for (int k = half * 256; k < half * 256 + 256; ++k) c += rowA[k] * wp[(size_t)k * 256];
    pl[t] = c;
  }
  __syncthreads();
  float val = 0.f;
  if (t < 256) val = pl[t] + pl[256 + t] + pb1[t];
  float mean = bsum8(t < 256 ? val : 0.f, r8) * (1.f / 256.f);
  float d = val - mean;
  float var = bsum8(t < 256 ? d * d : 0.f, r8) * (1.f / 256.f);
  if (t < 256) {
    float v = d * rsqrtf(var + 1e-5f) * plg[t] + plb[t];
    pp[b * 256 + t] = fmaxf(v, 0.f);
  }
}

// ---------------------------------------------------------------------------
// K4: out[b][pi][o] = LN_o(pp[b] @ pW2[:, pi-tile] + pb2). grid (96 pi, 4 bq),
// block 256: wave w handles 2 b rows, lane = o. pW2 tile staged in LDS.
__global__ __launch_bounds__(256) void k4_pfin(const float* __restrict__ pp,
                                               const float* __restrict__ pW2,
                                               const float* __restrict__ pb2,
                                               const float* __restrict__ ong,
                                               const float* __restrict__ onb,
                                               float* __restrict__ outp) {
  __shared__ __align__(16) float Ws[256 * 64];  // 64 KB
  __shared__ __align__(16) float As[8 * 260];
  const int pi = blockIdx.x, bq = blockIdx.y;
  const int t = threadIdx.x;
  const float* wp = pW2 + pi * 64;
  for (int i = t; i < 4096; i += 256) {
    int r = i >> 4, q = i & 15;
    *(float4*)&Ws[r * 64 + q * 4] = *(const float4*)(wp + (size_t)r * 6144 + q * 4);
  }
  for (int i = t; i < 512; i += 256) {
    int b = i >> 6, q = i & 63;
    *(float4*)&As[b * 260 + q * 4] = *(const float4*)(pp + (size_t)(bq * 8 + b) * 256 + q * 4);
  }
  __syncthreads();
  const int w = t >> 6, o = t & 63;
  const int bl = w * 2;  // local b pair
  float a0 = 0.f, a1 = 0.f;
  const float* ar0 = As + bl * 260;
  const float* ar1 = ar0 + 260;
#pragma unroll 8
  for (int k = 0; k < 256; ++k) {
    float wv = Ws[k * 64 + o];
    a0 += ar0[k] * wv;
    a1 += ar1[k] * wv;
  }
  float bias = pb2[pi * 64 + o];
  float gv = ong[o], bv = onb[o];
  float accs[2] = {a0 + bias, a1 + bias};
#pragma unroll
  for (int rr = 0; rr < 2; ++rr) {
    float a = accs[rr];
    float s = a;
    for (int off = 1; off < 64; off <<= 1) s += __shfl_xor(s, off);
    float mean = s * (1.f / 64.f);
    float d = a - mean;
    float q = d * d;
    for (int off = 1; off < 64; off <<= 1) q += __shfl_xor(q, off);
    float r = rsqrtf(q * (1.f / 64.f) + 1e-5f);
    int b = bq * 8 + bl + rr;
    outp[((size_t)b * 96 + pi) * 64 + o] = d * r * gv + bv;
  }
}

extern "C" void kernel_launch(void* const* d_in, const int* in_sizes, int n_in,
                              void* d_out, int out_size, void* d_ws, size_t ws_size,
                              hipStream_t stream) {
  (void)in_sizes; (void)n_in; (void)out_size; (void)ws_size;
  const float* x      = (const float*)d_in[0];
  const float* gW1    = (const float*)d_in[1];
  const float* gb1    = (const float*)d_in[2];
  const float* gln1_g = (const float*)d_in[3];
  const float* gln1_b = (const float*)d_in[4];
  const float* gW2    = (const float*)d_in[5];
  const float* gb2    = (const float*)d_in[6];
  const float* gln2_g = (const float*)d_in[7];
  const float* gln2_b = (const float*)d_in[8];
  const float* gW3    = (const float*)d_in[9];
  const float* gb3    = (const float*)d_in[10];
  const float* protos = (const float*)d_in[11];
  const float* temp   = (const float*)d_in[12];
  const float* eW1    = (const float*)d_in[13];
  const float* eb1    = (const float*)d_in[14];
  const float* eW2    = (const float*)d_in[15];
  const float* eb2    = (const float*)d_in[16];
  const float* fW1    = (const float*)d_in[17];
  const float* fb1    = (const float*)d_in[18];
  const float* fln_g  = (const float*)d_in[19];
  const float* fln_b  = (const float*)d_in[20];
  const float* fW2    = (const float*)d_in[21];
  const float* fb2    = (const float*)d_in[22];
  const float* ln_g   = (const float*)d_in[23];
  const float* ln_b   = (const float*)d_in[24];
  const float* pW1    = (const float*)d_in[25];
  const float* pb1    = (const float*)d_in[26];
  const float* pln_g  = (const float*)d_in[27];
  const float* pln_b  = (const float*)d_in[28];
  const float* pW2    = (const float*)d_in[29];
  const float* pb2    = (const float*)d_in[30];
  const float* on_g   = (const float*)d_in[31];
  const float* on_b   = (const float*)d_in[32];
  float* out = (float*)d_out;

  float* ws     = (float*)d_ws;
  float* part   = ws;               // 2,097,152 fl (8 MB)
  float* he_all = ws + 2097152;     // 131,072
  float* eo     = ws + 2228224;     // 131,072
  float* wgt    = ws + 2359296;     // 256
  float* pp     = ws + 2359552;     // 8,192

  k1_gemm1_he<<<528, 256, 0, stream>>>(x, gW1, eW1, eb1, part, he_all);
  k2_gtail_eg<<<96, 512, 0, stream>>>(part, gb1, gln1_g, gln1_b, gW2, gb2,
                                      gln2_g, gln2_b, gW3, gb3, protos, temp,
                                      he_all, eW2, wgt, eo);
  k3_fpath<<<32, 512, 0, stream>>>(eo, eb2, wgt, fW1, fb1, fln_g, fln_b,
                                   fW2, fb2, ln_g, ln_b, pW1, pb1, pln_g, pln_b, pp);
  k4_pfin<<<dim3(96, 4), 256, 0, stream>>>(pp, pW2, pb2, on_g, on_b, out);
}

// Round 8
// 309.519 us; speedup vs baseline: 3.7322x; 1.1571x over previous
//
#include <hip/hip_runtime.h>
#include <math.h>

// Shapes: B=32, S=512, I=64, H=512, E=8, P=96, O=64, EM=512; D = S*I = 32768.
#define DIMK 32768

__device__ __forceinline__ void fma4(float4& a, float s, const float4 w) {
  a.x += s * w.x; a.y += s * w.y; a.z += s * w.z; a.w += s * w.w;
}

// block sum, power-of-2 block (used with 256/512)
__device__ __forceinline__ float block_sum(float v, float* red, int n) {
  int t = threadIdx.x;
  red[t] = v;
  __syncthreads();
  for (int s = n >> 1; s > 0; s >>= 1) {
    if (t < s) red[t] += red[t + s];
    __syncthreads();
  }
  float r = red[0];
  __syncthreads();
  return r;
}

// block sum over 512 threads via shuffles
__device__ __forceinline__ float bsum8(float v, volatile float* r8) {
  for (int o = 1; o < 64; o <<= 1) v += __shfl_xor(v, o);
  const int w = threadIdx.x >> 6;
  __syncthreads();
  if ((threadIdx.x & 63) == 0) r8[w] = v;
  __syncthreads();
  float s = 0.f;
#pragma unroll
  for (int i = 0; i < 8; ++i) s += r8[i];
  return s;
}

// ---------------------------------------------------------------------------
// K1: bid<512: gemm1 k-split tile (46 µs proven); bid>=512: he_all (16 blocks).
__global__ __launch_bounds__(256) void k1_gemm1_he(const float* __restrict__ x,
                                                   const float* __restrict__ gW1,
                                                   const float* __restrict__ eW1,
                                                   const float* __restrict__ eb1,
                                                   float* __restrict__ part,
                                                   float* __restrict__ he_all) {
  __shared__ __align__(16) float S[18432];
  const int t = threadIdx.x;
  if (blockIdx.x < 512) {
    const int mt = blockIdx.x & 3, ks = blockIdx.x >> 2;
    const int m0 = mt * 128, k0 = ks * 256;
    float* As = S;          // 32 x 260
    float* Ws = S + 8320;   // 64 x 128
    for (int i = t; i < 2048; i += 256) {
      int b = i >> 6, q = i & 63;
      *(float4*)&As[b * 260 + q * 4] = *(const float4*)(x + (size_t)b * DIMK + k0 + q * 4);
    }
    const float* Wp = gW1 + (size_t)k0 * 512 + m0;
    float4 wreg[8];
#pragma unroll
    for (int j = 0; j < 8; ++j) {
      int i = t + j * 256, r = i >> 5, q = i & 31;
      wreg[j] = *(const float4*)(Wp + (size_t)r * 512 + q * 4);
    }
    const int mf = t & 31, bg = t >> 5;
    const int b0 = bg * 4;
    float4 acc[4];
#pragma unroll
    for (int j = 0; j < 4; ++j) acc[j] = make_float4(0.f, 0.f, 0.f, 0.f);
    const float* a0 = &As[b0 * 260];
    for (int s = 0; s < 4; ++s) {
      __syncthreads();
#pragma unroll
      for (int j = 0; j < 8; ++j) {
        int i = t + j * 256, r = i >> 5, q = i & 31;
        *(float4*)&Ws[r * 128 + q * 4] = wreg[j];
      }
      __syncthreads();
      if (s < 3) {
        const float* Wn = Wp + (size_t)(s + 1) * 64 * 512;
#pragma unroll
        for (int j = 0; j < 8; ++j) {
          int i = t + j * 256, r = i >> 5, q = i & 31;
          wreg[j] = *(const float4*)(Wn + (size_t)r * 512 + q * 4);
        }
      }
      const float* ab = a0 + s * 64;
#pragma unroll 8
      for (int k = 0; k < 64; ++k) {
        float4 wv = *(const float4*)&Ws[k * 128 + mf * 4];
        fma4(acc[0], ab[k], wv);
        fma4(acc[1], ab[260 + k], wv);
        fma4(acc[2], ab[520 + k], wv);
        fma4(acc[3], ab[780 + k], wv);
      }
    }
    float* op = part + ((size_t)ks * 32 + b0) * 512 + m0 + mf * 4;
#pragma unroll
    for (int j = 0; j < 4; ++j) *(float4*)(op + (size_t)j * 512) = acc[j];
  } else {
    const int v = blockIdx.x - 512;
    const int e = v >> 1, hs = v & 1;
    float* xs = S;          // 32 x 64
    float* Ws = S + 2048;   // 64 x 256
    for (int i = t; i < 512; i += 256) {
      int b = i >> 4, q = i & 15;
      *(float4*)&xs[b * 64 + q * 4] = *(const float4*)(x + (size_t)b * DIMK + 32704 + q * 4);
    }
    const float* w1 = eW1 + (size_t)e * 32768 + hs * 256;
    for (int i = t; i < 4096; i += 256) {
      int r = i >> 6, q = i & 63;
      *(float4*)&Ws[r * 256 + q * 4] = *(const float4*)(w1 + (size_t)r * 512 + q * 4);
    }
    __syncthreads();
    float acc[32];
#pragma unroll
    for (int b = 0; b < 32; ++b) acc[b] = 0.f;
#pragma unroll 4
    for (int k = 0; k < 64; ++k) {
      float wk = Ws[k * 256 + t];
#pragma unroll
      for (int b = 0; b < 32; ++b) acc[b] += xs[b * 64 + k] * wk;
    }
    float bb = eb1[e * 512 + hs * 256 + t];
    for (int b = 0; b < 32; ++b)
      he_all[((size_t)e * 32 + b) * 512 + hs * 256 + t] = fmaxf(acc[b] + bb, 0.f);
  }
}

// ---------------------------------------------------------------------------
// kred1: y1[b][m] = gb1[m] + sum_{ks<128} part[(ks*32+b)*512+m].
// grid (8 mh, 32 b), block 64 -> 256 blocks; 128 independent loads/thread.
__global__ __launch_bounds__(64) void kred1(const float* __restrict__ part,
                                            const float* __restrict__ gb1,
                                            float* __restrict__ y1) {
  const int m = blockIdx.x * 64 + threadIdx.x;
  const int b = blockIdx.y;
  const float* p = part + (size_t)b * 512 + m;
  float a0 = 0.f, a1 = 0.f, a2 = 0.f, a3 = 0.f;
#pragma unroll 8
  for (int ks = 0; ks < 128; ks += 4) {
    a0 += p[(size_t)(ks + 0) * 16384];
    a1 += p[(size_t)(ks + 1) * 16384];
    a2 += p[(size_t)(ks + 2) * 16384];
    a3 += p[(size_t)(ks + 3) * 16384];
  }
  y1[b * 512 + m] = gb1[m] + a0 + a1 + a2 + a3;
}

// ---------------------------------------------------------------------------
// k3: bid<32: h1 = relu(LN(y1)) (per-b). bid>=32: eW2 GEMM (full K) -> eo.
__global__ __launch_bounds__(512) void k3_ln_eg(const float* __restrict__ y1,
                                                const float* __restrict__ g1g, const float* __restrict__ g1b,
                                                const float* __restrict__ he_all, const float* __restrict__ eW2,
                                                float* __restrict__ h1, float* __restrict__ eo) {
  __shared__ __align__(16) float S[16512];
  __shared__ float r8[8];
  const int t = threadIdx.x;
  if (blockIdx.x < 32) {
    const int b = blockIdx.x;
    float a = y1[b * 512 + t];
    float mean = bsum8(a, r8) * (1.f / 512.f);
    float d = a - mean;
    float var = bsum8(d * d, r8) * (1.f / 512.f);
    h1[b * 512 + t] = fmaxf(d * rsqrtf(var + 1e-5f) * g1g[t] + g1b[t], 0.f);
  } else {
    const int v = blockIdx.x - 32;
    const int e = v >> 3, mt = v & 7;
    const int m0 = mt * 64;
    float* As = S;          // 32 x 260
    float* Ws = S + 8320;   // 128 x 64
    const int mf = t & 15, bg = t >> 4;
    float4 acc = make_float4(0.f, 0.f, 0.f, 0.f);
    const float* Ae = he_all + (size_t)e * 16384;
    const float* We = eW2 + (size_t)e * 262144 + m0;
    for (int kh = 0; kh < 2; ++kh) {
      __syncthreads();
      for (int i = t; i < 2048; i += 512) {
        int b = i >> 6, q = i & 63;
        *(float4*)&As[b * 260 + q * 4] =
            *(const float4*)(Ae + (size_t)b * 512 + kh * 256 + q * 4);
      }
      for (int sub = 0; sub < 2; ++sub) {
        __syncthreads();
        const float* wp = We + (size_t)(kh * 256 + sub * 128) * 512;
        for (int i = t; i < 2048; i += 512) {
          int r = i >> 4, q = i & 15;
          *(float4*)&Ws[r * 64 + q * 4] = *(const float4*)(wp + (size_t)r * 512 + q * 4);
        }
        __syncthreads();
        const float* ar = As + bg * 260 + sub * 128;
#pragma unroll 8
        for (int k = 0; k < 128; ++k)
          fma4(acc, ar[k], *(const float4*)&Ws[k * 64 + mf * 4]);
      }
    }
    *(float4*)(eo + ((size_t)e * 32 + bg) * 512 + m0 + mf * 4) = acc;
  }
}

// ---------------------------------------------------------------------------
// gemm_tile: C_part = A(32x512) @ W(512xM), one (64m x 32k) tile/block.
// grid (M/64, 16), block 256. Output zp[(kq*32+b)*M + m].
__global__ __launch_bounds__(256) void gemm_tile(const float* __restrict__ A,
                                                 const float* __restrict__ W,
                                                 float* __restrict__ outp, int M) {
  const int mt = blockIdx.x, kq = blockIdx.y;
  const int m0 = mt * 64, k0 = kq * 32;
  const int t = threadIdx.x;
  __shared__ float Ws[32 * 64];
  __shared__ float As[32 * 36];
  const float* Wp = W + (size_t)k0 * M + m0;
  for (int i = t; i < 512; i += 256) {
    int r = i >> 4, q = i & 15;
    *(float4*)&Ws[r * 64 + q * 4] = *(const float4*)(Wp + (size_t)r * M + q * 4);
  }
  {
    int b = t >> 3, q = t & 7;
    *(float4*)&As[b * 36 + q * 4] = *(const float4*)(A + (size_t)b * 512 + k0 + q * 4);
  }
  __syncthreads();
  const int mf = t & 15, b0 = (t >> 4) * 2;
  float4 acc0 = make_float4(0.f, 0.f, 0.f, 0.f), acc1 = acc0;
  const float* a0 = &As[b0 * 36];
  const float* a1 = a0 + 36;
#pragma unroll
  for (int k = 0; k < 32; ++k) {
    float4 wv = *(const float4*)&Ws[k * 64 + mf * 4];
    fma4(acc0, a0[k], wv);
    fma4(acc1, a1[k], wv);
  }
  float* op = outp + ((size_t)kq * 32 + b0) * M + m0 + mf * 4;
  *(float4*)op = acc0;
  *(float4*)(op + M) = acc1;
}

// ---------------------------------------------------------------------------
// red_ln: out = [relu](LN(sum_{kq<16} zp + bias)). grid 32, block M (512/256).
__global__ void red_ln(const float* __restrict__ zp, const float* __restrict__ bias,
                       const float* __restrict__ g, const float* __restrict__ bt,
                       float* __restrict__ outp, int M, int relu) {
  const int b = blockIdx.x, t = threadIdx.x;
  __shared__ float red[512];
  float a = bias[t];
  const float* p = zp + (size_t)b * M + t;
#pragma unroll
  for (int kq = 0; kq < 16; ++kq) a += p[(size_t)kq * 32 * M];
  float fM = 1.f / (float)M;
  float mean = block_sum(a, red, M) * fM;
  float d = a - mean;
  float var = block_sum(d * d, red, M) * fM;
  float v = d * rsqrtf(var + 1e-5f) * g[t] + bt[t];
  outp[b * M + t] = relu ? fmaxf(v, 0.f) : v;
}

// ---------------------------------------------------------------------------
// kgate: per-b: emb = h2@gW3+gb3 -> distances -> softmax -> wgt. 32 blk x 512.
__global__ __launch_bounds__(512) void kgate(const float* __restrict__ h2,
                                             const float* __restrict__ gW3,
                                             const float* __restrict__ gb3,
                                             const float* __restrict__ protos,
                                             const float* __restrict__ temp,
                                             float* __restrict__ wgt) {
  __shared__ float hb[512], embp[512], embs[128], d2s[8];
  const int b = blockIdx.x, t = threadIdx.x;
  hb[t] = h2[b * 512 + t];
  __syncthreads();
  {
    const int kh = t >> 7, m = t & 127;
    float c = 0.f;
    const float* w3 = gW3 + m;
#pragma unroll 8
    for (int k = kh * 128; k < kh * 128 + 128; ++k) c += hb[k] * w3[(size_t)k * 128];
    embp[t] = c;
  }
  __syncthreads();
  if (t < 128) embs[t] = gb3[t] + embp[t] + embp[128 + t] + embp[256 + t] + embp[384 + t];
  __syncthreads();
  {
    const int e = t >> 6, l = t & 63;
    float z0 = embs[l] - protos[e * 128 + l];
    float z1 = embs[l + 64] - protos[e * 128 + 64 + l];
    float q = z0 * z0 + z1 * z1;
    for (int o = 1; o < 64; o <<= 1) q += __shfl_xor(q, o);
    if (l == 0) d2s[e] = q;
  }
  __syncthreads();
  if (t == 0) {
    float tt = fminf(fmaxf(temp[0], 0.1f), 5.0f);
    float lg[8], mx = -1e30f;
#pragma unroll
    for (int e = 0; e < 8; ++e) {
      float dist = sqrtf(fmaxf(d2s[e], 1e-12f));
      lg[e] = -dist / tt;
      mx = fmaxf(mx, lg[e]);
    }
    float se = 0.f;
#pragma unroll
    for (int e = 0; e < 8; ++e) { lg[e] = expf(lg[e] - mx); se += lg[e]; }
#pragma unroll
    for (int e = 0; e < 8; ++e) wgt[b * 8 + e] = lg[e] / se;
  }
}

// ---------------------------------------------------------------------------
// kffuse: fused[b][m] = sum_e wgt[b,e]*(eo[e][b][m]+eb2[e][m]). 32 blk x 512.
__global__ __launch_bounds__(512) void kffuse(const float* __restrict__ eo,
                                              const float* __restrict__ eb2,
                                              const float* __restrict__ wgt,
                                              float* __restrict__ fused) {
  __shared__ float wl8[8];
  const int b = blockIdx.x, t = threadIdx.x;
  if (t < 8) wl8[t] = wgt[b * 8 + t];
  __syncthreads();
  float a = 0.f;
#pragma unroll
  for (int e = 0; e < 8; ++e)
    a += wl8[e] * (eo[((size_t)e * 32 + b) * 512 + t] + eb2[e * 512 + t]);
  fused[b * 512 + t] = a;
}

// ---------------------------------------------------------------------------
// K4: out[b][pi][o] = LN_o(pp[b] @ pW2[:,pi-tile] + pb2). grid (96,4), blk 256.
__global__ __launch_bounds__(256) void k4_pfin(const float* __restrict__ pp,
                                               const float* __restrict__ pW2,
                                               const float* __restrict__ pb2,
                                               const float* __restrict__ ong,
                                               const float* __restrict__ onb,
                                               float* __restrict__ outp) {
  __shared__ __align__(16) float Ws[256 * 64];
  __shared__ __align__(16) float As[8 * 260];
  const int pi = blockIdx.x, bq = blockIdx.y;
  const int t = threadIdx.x;
  const float* wp = pW2 + pi * 64;
  for (int i = t; i < 4096; i += 256) {
    int r = i >> 4, q = i & 15;
    *(float4*)&Ws[r * 64 + q * 4] = *(const float4*)(wp + (size_t)r * 6144 + q * 4);
  }
  for (int i = t; i < 512; i += 256) {
    int b = i >> 6, q = i & 63;
    *(float4*)&As[b * 260 + q * 4] = *(const float4*)(pp + (size_t)(bq * 8 + b) * 256 + q * 4);
  }
  __syncthreads();
  const int w = t >> 6, o = t & 63;
  const int bl = w * 2;
  float a0 = 0.f, a1 = 0.f;
  const float* ar0 = As + bl * 260;
  const float* ar1 = ar0 + 260;
#pragma unroll 8
  for (int k = 0; k < 256; ++k) {
    float wv = Ws[k * 64 + o];
    a0 += ar0[k] * wv;
    a1 += ar1[k] * wv;
  }
  float bias = pb2[pi * 64 + o];
  float gv = ong[o], bv = onb[o];
  float accs[2] = {a0 + bias, a1 + bias};
#pragma unroll
  for (int rr = 0; rr < 2; ++rr) {
    float a = accs[rr];
    float s = a;
    for (int off = 1; off < 64; off <<= 1) s += __shfl_xor(s, off);
    float mean = s * (1.f / 64.f);
    float d = a - mean;
    float q = d * d;
    for (int off = 1; off < 64; off <<= 1) q += __shfl_xor(q, off);
    float r = rsqrtf(q * (1.f / 64.f) + 1e-5f);
    int b = bq * 8 + bl + rr;
    outp[((size_t)b * 96 + pi) * 64 + o] = d * r * gv + bv;
  }
}

extern "C" void kernel_launch(void* const* d_in, const int* in_sizes, int n_in,
                              void* d_out, int out_size, void* d_ws, size_t ws_size,
                              hipStream_t stream) {
  (void)in_sizes; (void)n_in; (void)out_size; (void)ws_size;
  const float* x      = (const float*)d_in[0];
  const float* gW1    = (const float*)d_in[1];
  const float* gb1    = (const float*)d_in[2];
  const float* gln1_g = (const float*)d_in[3];
  const float* gln1_b = (const float*)d_in[4];
  const float* gW2    = (const float*)d_in[5];
  const float* gb2    = (const float*)d_in[6];
  const float* gln2_g = (const float*)d_in[7];
  const float* gln2_b = (const float*)d_in[8];
  const float* gW3    = (const float*)d_in[9];
  const float* gb3    = (const float*)d_in[10];
  const float* protos = (const float*)d_in[11];
  const float* temp   = (const float*)d_in[12];
  const float* eW1    = (const float*)d_in[13];
  const float* eb1    = (const float*)d_in[14];
  const float* eW2    = (const float*)d_in[15];
  const float* eb2    = (const float*)d_in[16];
  const float* fW1    = (const float*)d_in[17];
  const float* fb1    = (const float*)d_in[18];
  const float* fln_g  = (const float*)d_in[19];
  const float* fln_b  = (const float*)d_in[20];
  const float* fW2    = (const float*)d_in[21];
  const float* fb2    = (const float*)d_in[22];
  const float* ln_g   = (const float*)d_in[23];
  const float* ln_b   = (const float*)d_in[24];
  const float* pW1    = (const float*)d_in[25];
  const float* pb1    = (const float*)d_in[26];
  const float* pln_g  = (const float*)d_in[27];
  const float* pln_b  = (const float*)d_in[28];
  const float* pW2    = (const float*)d_in[29];
  const float* pb2    = (const float*)d_in[30];
  const float* on_g   = (const float*)d_in[31];
  const float* on_b   = (const float*)d_in[32];
  float* out = (float*)d_out;

  float* ws     = (float*)d_ws;
  float* part   = ws;               // 2,097,152
  float* he_all = ws + 2097152;     // 131,072
  float* eo     = ws + 2228224;     // 131,072
  float* y1     = ws + 2359296;     // 16,384
  float* h1     = ws + 2375680;     // 16,384
  float* zp     = ws + 2392064;     // 262,144 (16 kq x 32 x 512)
  float* h2     = ws + 2654208;     // 16,384
  float* wgt    = ws + 2670592;     // 256
  float* fused  = ws + 2670848;     // 16,384
  float* f1     = ws + 2687232;     // 16,384
  float* lastv  = ws + 2703616;     // 16,384
  float* pp     = ws + 2720000;     // 8,192  (end 2,728,192 fl = 10.9 MB)

  k1_gemm1_he<<<528, 256, 0, stream>>>(x, gW1, eW1, eb1, part, he_all);
  kred1<<<dim3(8, 32), 64, 0, stream>>>(part, gb1, y1);
  k3_ln_eg<<<96, 512, 0, stream>>>(y1, gln1_g, gln1_b, he_all, eW2, h1, eo);
  gemm_tile<<<dim3(8, 16), 256, 0, stream>>>(h1, gW2, zp, 512);
  red_ln<<<32, 512, 0, stream>>>(zp, gb2, gln2_g, gln2_b, h2, 512, 1);
  kgate<<<32, 512, 0, stream>>>(h2, gW3, gb3, protos, temp, wgt);
  kffuse<<<32, 512, 0, stream>>>(eo, eb2, wgt, fused);
  gemm_tile<<<dim3(8, 16), 256, 0, stream>>>(fused, fW1, zp, 512);
  red_ln<<<32, 512, 0, stream>>>(zp, fb1, fln_g, fln_b, f1, 512, 1);
  gemm_tile<<<dim3(8, 16), 256, 0, stream>>>(f1, fW2, zp, 512);
  red_ln<<<32, 512, 0, stream>>>(zp, fb2, ln_g, ln_b, lastv, 512, 0);
  gemm_tile<<<dim3(4, 16), 256, 0, stream>>>(lastv, pW1, zp, 256);
  red_ln<<<32, 256, 0, stream>>>(zp, pb1, pln_g, pln_b, pp, 256, 1);
  k4_pfin<<<dim3(96, 4), 256, 0, stream>>>(pp, pW2, pb2, on_g, on_b, out);
}